// Round 4
// baseline (268.441 us; speedup 1.0000x reference)
//
#include <hip/hip_runtime.h>

// SNN temporal scan, T=16, K=8 nested thresholds. Bit-exact vs numpy f32.
//
// R4 structure:
//  - ALL 17 loads (bias + 16 steps) issued before any store: vmcnt is in-order,
//    so per-iteration load waits are satisfied by oldest loads only; stores
//    (always newest outstanding) can never gate a load-use. One latency region
//    per wave instead of 16.
//  - Integer-exponent spike path: positive floats compare as ints, and all
//    2^-k scalings are exact bit-subtractions of k<<23. First-fired threshold
//    k* = clamp(ceil((bits(0.75*th)-bits(|m|))/2^23),0), fire iff k*<=7.
//    spike = sign | (bits(th) - k*<<23); eout increment = sign|(bits(q_t)-k*<<23)
//    with q_t = rn(th/t) (7 odd-base IEEE divs; even non-pow2 by exact halving).
//  - ein: d/t as exact pow2 multiply when t is a power of 2, IEEE div otherwise
//    (unavoidable, matches reference rounding).

#define T_STEPS 16

typedef float v2f __attribute__((ext_vector_type(2)));

__global__ __launch_bounds__(256, 8) void snn_scan_kernel(
    const float* __restrict__ x,
    const float* __restrict__ thresh_p,
    float* __restrict__ out,
    int N2)  // float2 groups per timestep slice
{
    const int i = blockIdx.x * blockDim.x + threadIdx.x;
    if (i >= N2) return;

    const v2f* __restrict__ xv = (const v2f*)x;
    v2f* __restrict__ ov = (v2f*)out;

    // ---- all loads first (no store may precede any load in vmcnt order) ----
    const v2f b2 = xv[i];
    v2f buf[T_STEPS];
#pragma unroll
    for (int t = 0; t < T_STEPS; ++t) buf[t] = xv[(t + 1) * N2 + i];

    // uniform scalars (s_load / SALU)
    const float th = *thresh_p;
    const unsigned vbits  = __float_as_uint(0.75f * th);  // bits(rn(0.75*th))
    const unsigned thbits = __float_as_uint(th);

    // q_t = rn(th/t) building blocks: 7 odd-base divs, uniform across wave
    const float q3 = th / 3.0f,  q5 = th / 5.0f,  q7 = th / 7.0f,
                q9 = th / 9.0f,  q11 = th / 11.0f, q13 = th / 13.0f,
                q15 = th / 15.0f;

    // output slice 0 = zeros (issued after all loads)
    {
        v2f z; z.x = 0.f; z.y = 0.f;
        __builtin_nontemporal_store(z, ov + i);
    }

    float mem0 = 0.f, mem1 = 0.f;
    const float bias0 = b2.x, bias1 = b2.y;
    float ein0 = bias0, ein1 = bias1;   // exp_in init = bias
    float eout0 = 0.f, eout1 = 0.f;

#pragma unroll
    for (int t = 1; t <= T_STEPS; ++t) {
        const float xi0 = buf[t - 1].x, xi1 = buf[t - 1].y;

        const bool  tp2 = (t & (t - 1)) == 0;     // compile-time per iter
        const float rt  = 1.0f / (float)t;        // exact pow2 when tp2
        // q_t = rn(th/t); even non-pow2 derived by exact *0.5/*0.25 scalings
        float q_t;
        switch (t) {                               // resolved at compile time
            case 1: case 2: case 4: case 8: case 16: q_t = th * rt; break;
            case 3:  q_t = q3;          break;
            case 5:  q_t = q5;          break;
            case 6:  q_t = q3 * 0.5f;   break;
            case 7:  q_t = q7;          break;
            case 9:  q_t = q9;          break;
            case 10: q_t = q5 * 0.5f;   break;
            case 11: q_t = q11;         break;
            case 12: q_t = q3 * 0.25f;  break;
            case 13: q_t = q13;         break;
            case 14: q_t = q7 * 0.5f;   break;
            default: q_t = q15;         break;     // t = 15
        }
        const unsigned qbits = __float_as_uint(q_t);

        auto stepj = [&](float& mem, float& ein, float& eout,
                         float xi, float bias) -> float {
            // mem = mem + xi - bias + exp_in - exp_out (left-to-right order)
            const float m = (((mem + xi) - bias) + ein) - eout;
            const unsigned mb  = __float_as_uint(m);
            const unsigned u   = mb & 0x7fffffffu;        // bits(|m|), int-orderable
            const int diff     = (int)(vbits - u);
            int k = (diff + 0x7fffff) >> 23;              // ceil(diff / 2^23)
            k = k < 0 ? 0 : k;                            // first-fired threshold
            const bool fire = (k <= 7);
            const unsigned ksh = (unsigned)k << 23;
            const unsigned sgn = mb & 0x80000000u;
            const unsigned sb  = fire ? (sgn | (thbits - ksh)) : 0u;  // ±th*2^-k
            const unsigned qb  = fire ? (sgn | (qbits - ksh)) : 0u;   // ±rn(th/t)*2^-k
            const float s = __uint_as_float(sb);
            mem = m - s;
            const float d = xi - bias;
            if (tp2) ein = ein + d * rt;          // exact == d/t for pow2 t
            else     ein = ein + d / (float)t;    // IEEE div (non-pow2 t)
            eout = eout + __uint_as_float(qb);
            return s;
        };

        v2f sp;
        sp.x = stepj(mem0, ein0, eout0, xi0, bias0);
        sp.y = stepj(mem1, ein1, eout1, xi1, bias1);
        __builtin_nontemporal_store(sp, ov + t * N2 + i);
    }
}

extern "C" void kernel_launch(void* const* d_in, const int* in_sizes, int n_in,
                              void* d_out, int out_size, void* d_ws, size_t ws_size,
                              hipStream_t stream) {
    const float* x      = (const float*)d_in[0];
    const float* thresh = (const float*)d_in[1];
    float* out = (float*)d_out;

    const int N  = in_sizes[0] / (T_STEPS + 1);  // elements per timestep slice
    const int N2 = N / 2;                        // float2 groups

    const int block = 256;
    const int grid  = (N2 + block - 1) / block;
    snn_scan_kernel<<<grid, block, 0, stream>>>(x, thresh, out, N2);
}

// Round 5
// 257.616 us; speedup vs baseline: 1.0420x; 1.0420x over previous
//
#include <hip/hip_runtime.h>

// SNN temporal scan, T=16, K=8 nested thresholds. Bit-exact vs numpy f32
// (absmax 0.0 in R1-R4).
//
// R5: R4's all-loads-first structure, but FORCED with sched_barrier(0).
// R4's counters showed VGPR=32 -- the compiler sank the 16 up-front loads
// back into the loop (34 data regs didn't fit its pressure heuristic), so
// each wave had ~1 load in flight and stalled ~650 cyc/iteration.
// The opaque scheduling fence pins all 17 loads before any compute/store:
// 8 KB in flight per wave >> latency-BW product (~2.3 KB/SIMD), so the
// kernel becomes BW-bound instead of latency-bound.
//
// Numerics (all exact substitutions):
//  - mem update keeps reference's left-to-right add order
//  - first-fired threshold via integer exponent arithmetic: positive floats
//    compare as ints; 2^-k scalings are exact bit-subtractions of k<<23
//  - spike = sign | (bits(th) - k<<23); eout += sign | (bits(rn(th/t)) - k<<23)
//  - ein += d/t: exact pow2 multiply when t is a power of two, IEEE div else

#define T_STEPS 16

typedef float v2f __attribute__((ext_vector_type(2)));

__global__ __launch_bounds__(256, 8) void snn_scan_kernel(
    const float* __restrict__ x,
    const float* __restrict__ thresh_p,
    float* __restrict__ out,
    int N2)  // float2 groups per timestep slice
{
    const int i = blockIdx.x * blockDim.x + threadIdx.x;
    if (i >= N2) return;

    const v2f* __restrict__ xv = (const v2f*)x;
    v2f* __restrict__ ov = (v2f*)out;

    // ---- issue ALL loads, then fence so nothing reorders across ----
    const float th = *thresh_p;
    const v2f b2 = xv[i];
    v2f buf[T_STEPS];
#pragma unroll
    for (int t = 0; t < T_STEPS; ++t) buf[t] = xv[(t + 1) * N2 + i];
    __builtin_amdgcn_sched_barrier(0);  // pin: loads stay issued up front

    // uniform scalars
    const unsigned vbits  = __float_as_uint(0.75f * th);  // bits(rn(0.75*th))
    const unsigned thbits = __float_as_uint(th);
    const float q3 = th / 3.0f,  q5 = th / 5.0f,  q7 = th / 7.0f,
                q9 = th / 9.0f,  q11 = th / 11.0f, q13 = th / 13.0f,
                q15 = th / 15.0f;

    // output slice 0 = zeros
    {
        v2f z; z.x = 0.f; z.y = 0.f;
        __builtin_nontemporal_store(z, ov + i);
    }

    float mem0 = 0.f, mem1 = 0.f;
    const float bias0 = b2.x, bias1 = b2.y;
    float ein0 = bias0, ein1 = bias1;   // exp_in init = bias
    float eout0 = 0.f, eout1 = 0.f;

#pragma unroll
    for (int t = 1; t <= T_STEPS; ++t) {
        const float xi0 = buf[t - 1].x, xi1 = buf[t - 1].y;

        const bool  tp2 = (t & (t - 1)) == 0;     // compile-time per iter
        const float rt  = 1.0f / (float)t;        // exact pow2 when tp2
        float q_t;                                // rn(th/t), exact derivations
        switch (t) {
            case 1: case 2: case 4: case 8: case 16: q_t = th * rt; break;
            case 3:  q_t = q3;          break;
            case 5:  q_t = q5;          break;
            case 6:  q_t = q3 * 0.5f;   break;
            case 7:  q_t = q7;          break;
            case 9:  q_t = q9;          break;
            case 10: q_t = q5 * 0.5f;   break;
            case 11: q_t = q11;         break;
            case 12: q_t = q3 * 0.25f;  break;
            case 13: q_t = q13;         break;
            case 14: q_t = q7 * 0.5f;   break;
            default: q_t = q15;         break;     // t = 15
        }
        const unsigned qbits = __float_as_uint(q_t);

        auto stepj = [&](float& mem, float& ein, float& eout,
                         float xi, float bias) -> float {
            // mem = mem + xi - bias + exp_in - exp_out (left-to-right order)
            const float m = (((mem + xi) - bias) + ein) - eout;
            const unsigned mb  = __float_as_uint(m);
            const unsigned u   = mb & 0x7fffffffu;        // bits(|m|)
            const int diff     = (int)(vbits - u);
            int k = (diff + 0x7fffff) >> 23;              // ceil(diff / 2^23)
            k = k < 0 ? 0 : k;                            // first-fired k
            const bool fire = (k <= 7);
            const unsigned ksh = (unsigned)k << 23;
            const unsigned sgn = mb & 0x80000000u;
            const unsigned sb  = fire ? (sgn | (thbits - ksh)) : 0u;  // ±th*2^-k
            const unsigned qb  = fire ? (sgn | (qbits - ksh)) : 0u;   // ±q_t*2^-k
            const float s = __uint_as_float(sb);
            mem = m - s;
            const float d = xi - bias;
            if (tp2) ein = ein + d * rt;          // exact == d/t for pow2 t
            else     ein = ein + d / (float)t;    // IEEE div (non-pow2 t)
            eout = eout + __uint_as_float(qb);
            return s;
        };

        v2f sp;
        sp.x = stepj(mem0, ein0, eout0, xi0, bias0);
        sp.y = stepj(mem1, ein1, eout1, xi1, bias1);
        __builtin_nontemporal_store(sp, ov + t * N2 + i);
    }
}

extern "C" void kernel_launch(void* const* d_in, const int* in_sizes, int n_in,
                              void* d_out, int out_size, void* d_ws, size_t ws_size,
                              hipStream_t stream) {
    const float* x      = (const float*)d_in[0];
    const float* thresh = (const float*)d_in[1];
    float* out = (float*)d_out;

    const int N  = in_sizes[0] / (T_STEPS + 1);  // elements per timestep slice
    const int N2 = N / 2;                        // float2 groups

    const int block = 256;
    const int grid  = (N2 + block - 1) / block;
    snn_scan_kernel<<<grid, block, 0, stream>>>(x, thresh, out, N2);
}